// Round 1
// baseline (279.986 us; speedup 1.0000x reference)
//
#include <hip/hip_runtime.h>
#include <math.h>

#define HH 384
#define WW 384
#define W4 96           // WW / 4
#define NIMG 272        // 16 * 17
#define TOTAL_VEC (NIMG * HH * W4)   // 10,027,008

__device__ __forceinline__ float4 hmax_row(const float* __restrict__ row, int x0) {
    // row is the start of a W-wide row; x0 = x4*4, aligned for float4
    float4 c = *(const float4*)(row + x0);
    float l = (x0 > 0)        ? row[x0 - 1] : -INFINITY;
    float r = (x0 + 4 < WW)   ? row[x0 + 4] : -INFINITY;
    float4 h;
    h.x = fmaxf(fmaxf(l,   c.x), c.y);
    h.y = fmaxf(fmaxf(c.x, c.y), c.z);
    h.z = fmaxf(fmaxf(c.y, c.z), c.w);
    h.w = fmaxf(fmaxf(c.z, c.w), r);
    return h;
}

__device__ __forceinline__ float peak_val(float m, float v) {
    // peak iff v equals the 3x3 max (exact fp equality, same as JAX) and
    // sigmoid(v) > 0.05
    float prob = 1.0f / (1.0f + expf(-v));
    return (m == v && prob > 0.05f) ? prob : 0.0f;
}

__global__ __launch_bounds__(256) void
heatmap_peaks_kernel(const float* __restrict__ in, float* __restrict__ out) {
    int vi = blockIdx.x * 256 + threadIdx.x;
    if (vi >= TOTAL_VEC) return;

    int x4   = vi % W4;
    int rest = vi / W4;
    int y    = rest % HH;
    int bk   = rest / HH;

    const float* img = in + (size_t)bk * (HH * WW);
    int x0 = x4 * 4;

    const float* rowc = img + (size_t)y * WW;
    float4 c = *(const float4*)(rowc + x0);

    // horizontal 3-max of center row (plus halo)
    float lc = (x0 > 0)      ? rowc[x0 - 1] : -INFINITY;
    float rc = (x0 + 4 < WW) ? rowc[x0 + 4] : -INFINITY;
    float4 hc;
    hc.x = fmaxf(fmaxf(lc,  c.x), c.y);
    hc.y = fmaxf(fmaxf(c.x, c.y), c.z);
    hc.z = fmaxf(fmaxf(c.y, c.z), c.w);
    hc.w = fmaxf(fmaxf(c.z, c.w), rc);

    float4 ht, hb;
    if (y > 0) {
        ht = hmax_row(img + (size_t)(y - 1) * WW, x0);
    } else {
        ht = make_float4(-INFINITY, -INFINITY, -INFINITY, -INFINITY);
    }
    if (y < HH - 1) {
        hb = hmax_row(img + (size_t)(y + 1) * WW, x0);
    } else {
        hb = make_float4(-INFINITY, -INFINITY, -INFINITY, -INFINITY);
    }

    float4 m;
    m.x = fmaxf(fmaxf(ht.x, hc.x), hb.x);
    m.y = fmaxf(fmaxf(ht.y, hc.y), hb.y);
    m.z = fmaxf(fmaxf(ht.z, hc.z), hb.z);
    m.w = fmaxf(fmaxf(ht.w, hc.w), hb.w);

    float4 o;
    o.x = peak_val(m.x, c.x);
    o.y = peak_val(m.y, c.y);
    o.z = peak_val(m.z, c.z);
    o.w = peak_val(m.w, c.w);

    *(float4*)(out + (size_t)vi * 4) = o;
}

extern "C" void kernel_launch(void* const* d_in, const int* in_sizes, int n_in,
                              void* d_out, int out_size, void* d_ws, size_t ws_size,
                              hipStream_t stream) {
    const float* in = (const float*)d_in[0];
    float* out = (float*)d_out;
    int blocks = (TOTAL_VEC + 255) / 256;  // 39168
    heatmap_peaks_kernel<<<blocks, 256, 0, stream>>>(in, out);
}

// Round 2
// 272.729 us; speedup vs baseline: 1.0266x; 1.0266x over previous
//
#include <hip/hip_runtime.h>
#include <math.h>

#define HH 384
#define WW 384
#define W8 48            // WW / 8
#define NIMG 272         // 16 * 17
#define TOTAL_THR (NIMG * HH * W8)   // 5,013,504 = 19584 * 256 exactly

__device__ __forceinline__ float sigmoid_peak(float m, float v) {
    float prob = 1.0f / (1.0f + expf(-v));
    return (m == v && prob > 0.05f) ? prob : 0.0f;
}

__global__ __launch_bounds__(256) void
heatmap_peaks_kernel(const float* __restrict__ in, float* __restrict__ out) {
    int vi   = blockIdx.x * 256 + threadIdx.x;
    int lane = threadIdx.x & 63;

    int x8   = vi % W8;
    int rest = vi / W8;
    int y    = rest % HH;
    int bk   = rest / HH;

    const float* img  = in + (size_t)bk * (HH * WW);
    int x0 = x8 * 8;
    const float* rowc = img + (size_t)y * WW + x0;
    const float* rowt = rowc - WW;
    const float* rowb = rowc + WW;

    const float NEG = -INFINITY;
    bool has_t = (y > 0);
    bool has_b = (y < HH - 1);

    float4 c0 = *(const float4*)(rowc);
    float4 c1 = *(const float4*)(rowc + 4);
    float4 t0, t1, b0, b1;
    if (has_t) { t0 = *(const float4*)(rowt); t1 = *(const float4*)(rowt + 4); }
    else       { t0 = make_float4(NEG,NEG,NEG,NEG); t1 = t0; }
    if (has_b) { b0 = *(const float4*)(rowb); b1 = *(const float4*)(rowb + 4); }
    else       { b0 = make_float4(NEG,NEG,NEG,NEG); b1 = b0; }

    // halo values via cross-lane shuffle: lane-1's last element is our x0-1,
    // lane+1's first element is our x0+8. Executed uniformly by all lanes.
    float lc = __shfl_up(c1.w, 1);
    float lt = __shfl_up(t1.w, 1);
    float lb = __shfl_up(b1.w, 1);
    float rc = __shfl_down(c0.x, 1);
    float rt = __shfl_down(t0.x, 1);
    float rb = __shfl_down(b0.x, 1);

    // fix up row edges and wave edges
    if (x8 == 0) {
        lc = NEG; lt = NEG; lb = NEG;
    } else if (lane == 0) {
        lc = rowc[-1];
        lt = has_t ? rowt[-1] : NEG;
        lb = has_b ? rowb[-1] : NEG;
    }
    if (x8 == W8 - 1) {
        rc = NEG; rt = NEG; rb = NEG;
    } else if (lane == 63) {
        rc = rowc[8];
        rt = has_t ? rowt[8] : NEG;
        rb = has_b ? rowb[8] : NEG;
    }

    float cv[8] = {c0.x,c0.y,c0.z,c0.w,c1.x,c1.y,c1.z,c1.w};
    float tv[8] = {t0.x,t0.y,t0.z,t0.w,t1.x,t1.y,t1.z,t1.w};
    float bv[8] = {b0.x,b0.y,b0.z,b0.w,b1.x,b1.y,b1.z,b1.w};

    // horizontal 3-max per row
    float hc[8], ht[8], hb[8];
    hc[0] = fmaxf(fmaxf(lc, cv[0]), cv[1]);
    ht[0] = fmaxf(fmaxf(lt, tv[0]), tv[1]);
    hb[0] = fmaxf(fmaxf(lb, bv[0]), bv[1]);
#pragma unroll
    for (int i = 1; i < 7; ++i) {
        hc[i] = fmaxf(fmaxf(cv[i-1], cv[i]), cv[i+1]);
        ht[i] = fmaxf(fmaxf(tv[i-1], tv[i]), tv[i+1]);
        hb[i] = fmaxf(fmaxf(bv[i-1], bv[i]), bv[i+1]);
    }
    hc[7] = fmaxf(fmaxf(cv[6], cv[7]), rc);
    ht[7] = fmaxf(fmaxf(tv[6], tv[7]), rt);
    hb[7] = fmaxf(fmaxf(bv[6], bv[7]), rb);

    float o[8];
#pragma unroll
    for (int i = 0; i < 8; ++i) {
        float m = fmaxf(fmaxf(ht[i], hc[i]), hb[i]);
        o[i] = sigmoid_peak(m, cv[i]);
    }

    float* op = out + (size_t)vi * 8;
    *(float4*)(op)     = make_float4(o[0], o[1], o[2], o[3]);
    *(float4*)(op + 4) = make_float4(o[4], o[5], o[6], o[7]);
}

extern "C" void kernel_launch(void* const* d_in, const int* in_sizes, int n_in,
                              void* d_out, int out_size, void* d_ws, size_t ws_size,
                              hipStream_t stream) {
    const float* in = (const float*)d_in[0];
    float* out = (float*)d_out;
    int blocks = TOTAL_THR / 256;  // 19584
    heatmap_peaks_kernel<<<blocks, 256, 0, stream>>>(in, out);
}

// Round 3
// 270.857 us; speedup vs baseline: 1.0337x; 1.0069x over previous
//
#include <hip/hip_runtime.h>
#include <math.h>

#define HH 384
#define WW 384
#define W8 48            // WW / 8
#define NIMG 272         // 16 * 17
#define TOTAL_THR (NIMG * HH * W8)   // 5,013,504 = 19584 * 256 exactly

__device__ __forceinline__ float fast_sigmoid(float v) {
    // v_exp_f32 + v_rcp_f32 path; ~1-2 ulp, far inside the 0.0199 tolerance
    return __fdividef(1.0f, 1.0f + __expf(-v));
}

__global__ __launch_bounds__(256) void
heatmap_peaks_kernel(const float* __restrict__ in, float* __restrict__ out) {
    int vi   = blockIdx.x * 256 + threadIdx.x;
    int lane = threadIdx.x & 63;

    int x8   = vi % W8;
    int rest = vi / W8;
    int y    = rest % HH;
    int bk   = rest / HH;

    const float* rowc = in + (size_t)bk * (HH * WW) + (size_t)y * WW + x8 * 8;
    const float* rowt = rowc - WW;
    const float* rowb = rowc + WW;

    const float NEG = -INFINITY;
    bool has_t = (y > 0);
    bool has_b = (y < HH - 1);

    float4 c0 = *(const float4*)(rowc);
    float4 c1 = *(const float4*)(rowc + 4);
    float4 t0, t1, b0, b1;
    if (has_t) { t0 = *(const float4*)(rowt); t1 = *(const float4*)(rowt + 4); }
    else       { t0 = make_float4(NEG,NEG,NEG,NEG); t1 = t0; }
    if (has_b) { b0 = *(const float4*)(rowb); b1 = *(const float4*)(rowb + 4); }
    else       { b0 = make_float4(NEG,NEG,NEG,NEG); b1 = b0; }

    float cv[8] = {c0.x,c0.y,c0.z,c0.w,c1.x,c1.y,c1.z,c1.w};
    float tv[8] = {t0.x,t0.y,t0.z,t0.w,t1.x,t1.y,t1.z,t1.w};
    float bv[8] = {b0.x,b0.y,b0.z,b0.w,b1.x,b1.y,b1.z,b1.w};

    // vertical 3-max per column (v_max3), then horizontal 3-max of vm
    float vm[8];
#pragma unroll
    for (int i = 0; i < 8; ++i)
        vm[i] = fmaxf(fmaxf(tv[i], cv[i]), bv[i]);

    // column-max halos: only vm needs to cross thread boundaries
    float lvm = __shfl_up(vm[7], 1);
    float rvm = __shfl_down(vm[0], 1);

    if (x8 == 0) {
        lvm = NEG;
    } else if (lane == 0) {
        float tt = has_t ? rowt[-1] : NEG;
        float bb = has_b ? rowb[-1] : NEG;
        lvm = fmaxf(fmaxf(tt, rowc[-1]), bb);
    }
    if (x8 == W8 - 1) {
        rvm = NEG;
    } else if (lane == 63) {
        float tt = has_t ? rowt[8] : NEG;
        float bb = has_b ? rowb[8] : NEG;
        rvm = fmaxf(fmaxf(tt, rowc[8]), bb);
    }

    float m[8];
    m[0] = fmaxf(fmaxf(lvm, vm[0]), vm[1]);
#pragma unroll
    for (int i = 1; i < 7; ++i)
        m[i] = fmaxf(fmaxf(vm[i-1], vm[i]), vm[i+1]);
    m[7] = fmaxf(fmaxf(vm[6], vm[7]), rvm);

    float o[8];
#pragma unroll
    for (int i = 0; i < 8; ++i) {
        float prob = fast_sigmoid(cv[i]);
        o[i] = (m[i] == cv[i] && prob > 0.05f) ? prob : 0.0f;
    }

    float* op = out + (size_t)vi * 8;
    *(float4*)(op)     = make_float4(o[0], o[1], o[2], o[3]);
    *(float4*)(op + 4) = make_float4(o[4], o[5], o[6], o[7]);
}

extern "C" void kernel_launch(void* const* d_in, const int* in_sizes, int n_in,
                              void* d_out, int out_size, void* d_ws, size_t ws_size,
                              hipStream_t stream) {
    const float* in = (const float*)d_in[0];
    float* out = (float*)d_out;
    int blocks = TOTAL_THR / 256;  // 19584
    heatmap_peaks_kernel<<<blocks, 256, 0, stream>>>(in, out);
}